// Round 8
// baseline (96.786 us; speedup 1.0000x reference)
//
#include <hip/hip_runtime.h>

#define N 1536

// ---------------- K1: node encoder + message projection ----------------
// 256 blocks x 512 threads; 6 rows/block, float4 weight staging.
__global__ __launch_bounds__(512) void enc_kernel(
    const float* __restrict__ x, const float* __restrict__ W1, const float* __restrict__ b1,
    const float* __restrict__ W2, const float* __restrict__ b2,
    const float* __restrict__ Wm,
    float* __restrict__ h, float* __restrict__ p)
{
    __shared__ float sW2[64 * 64];
    __shared__ float sWm[64 * 64];
    __shared__ float buf1[6][64];
    __shared__ float buf2[6][64];
    int t = threadIdx.x;
    int w = t >> 6, c = t & 63;
    int i0 = blockIdx.x * 6;

    {
        const float4* W2v = (const float4*)W2;
        const float4* Wmv = (const float4*)Wm;
        float4* s2 = (float4*)sW2;
        float4* sm = (float4*)sWm;
        #pragma unroll
        for (int i = t; i < 1024; i += 512) { s2[i] = W2v[i]; sm[i] = Wmv[i]; }
    }

    if (w < 6) {
        int row = i0 + w;
        float4 xv = ((const float4*)x)[row];
        float h1 = xv.x * W1[0 * 64 + c] + xv.y * W1[1 * 64 + c]
                 + xv.z * W1[2 * 64 + c] + xv.w * W1[3 * 64 + c] + b1[c];
        buf1[w][c] = fmaxf(0.f, h1);
    }
    __syncthreads();

    if (w < 6) {
        int row = i0 + w;
        float h2 = b2[c];
        #pragma unroll
        for (int k = 0; k < 64; ++k) h2 = fmaf(buf1[w][k], sW2[k * 64 + c], h2);
        h2 = fmaxf(0.f, h2);
        h[row * 64 + c] = h2;
        buf2[w][c] = h2;

        float pv = 0.f;
        #pragma unroll
        for (int k = 0; k < 64; ++k) pv = fmaf(buf2[w][k], sWm[k * 64 + c], pv);
        p[row * 64 + c] = pv;
    }
}

// ---------------- K2: message-pass partials (2-D tiled N^2) ----------------
// Grid 256 = 64 row-groups x 4 j-slices; 1024 threads (16 waves), 1 block/CU.
// Block (ig, js): rows [ig*24, ig*24+24), j in [js*384, js*384+384).
// part[js][row][c] = sum_{j in slice} max(p[j,c], q[row,c]),  q = p[row,c]-bm[c]
#define RI2 24
#define JS  4
#define JPB (N / JS)     // 384 j per block
#define JPW (JPB / 16)   // 24 j per wave
#define JB  8            // load batch depth
__global__ __launch_bounds__(1024, 4) void msgA_kernel(
    const float* __restrict__ p, const float* __restrict__ bm,
    float* __restrict__ part)
{
    __shared__ float qs[RI2][64];      // 6 KB
    __shared__ float red[16][12][64];  // 48 KB, reused over 2 row-tiles
    int t = threadIdx.x;
    int c = t & 63, g = t >> 6;
    int ig = blockIdx.x >> 2, js = blockIdx.x & 3;
    int i0 = ig * RI2;

    // stage q rows once per block (saves per-wave global re-reads)
    for (int e = t; e < RI2 * 64; e += 1024) {
        int r = e >> 6, cc = e & 63;
        qs[r][cc] = p[(i0 + r) * 64 + cc] - bm[cc];
    }
    __syncthreads();

    float q[RI2];
    #pragma unroll
    for (int r = 0; r < RI2; ++r) q[r] = qs[r][c];

    const float* pw = p + (js * JPB + g * JPW) * 64 + c;
    float acc[RI2];
    #pragma unroll
    for (int r = 0; r < RI2; ++r) acc[r] = 0.f;

    float pj0[JB], pj1[JB];
    #pragma unroll
    for (int u = 0; u < JB; ++u) pj0[u] = pw[u * 64];

    #pragma unroll
    for (int jj = 0; jj < JPW / JB; ++jj) {   // 3 batches of 8
        if (jj + 1 < JPW / JB) {
            if ((jj & 1) == 0) {
                #pragma unroll
                for (int u = 0; u < JB; ++u) pj1[u] = pw[((jj + 1) * JB + u) * 64];
            } else {
                #pragma unroll
                for (int u = 0; u < JB; ++u) pj0[u] = pw[((jj + 1) * JB + u) * 64];
            }
        }
        if ((jj & 1) == 0) {
            #pragma unroll
            for (int u = 0; u < JB; ++u) {
                #pragma unroll
                for (int r = 0; r < RI2; ++r) acc[r] += fmaxf(pj0[u], q[r]);
            }
        } else {
            #pragma unroll
            for (int u = 0; u < JB; ++u) {
                #pragma unroll
                for (int r = 0; r < RI2; ++r) acc[r] += fmaxf(pj1[u], q[r]);
            }
        }
    }

    // reduce 16 waves, 2 row-tiles of 12
    #pragma unroll
    for (int rt = 0; rt < 2; ++rt) {
        #pragma unroll
        for (int rr = 0; rr < 12; ++rr) red[g][rr][c] = acc[rt * 12 + rr];
        __syncthreads();
        if (t < 12 * 64) {
            int rr = t >> 6, cc = t & 63;
            float s = 0.f;
            #pragma unroll
            for (int gg = 0; gg < 16; ++gg) s += red[gg][rr][cc];
            part[(js * N + i0 + rt * 12 + rr) * 64 + cc] = s;
        }
        if (rt == 0) __syncthreads();
    }
}

// ---------------- K3: reduce partials + update MLP + heads ----------------
// 64 blocks x 1024 threads, 24 rows per block.
#define RI3 24
__global__ __launch_bounds__(1024) void upd_kernel(
    const float* __restrict__ p, const float* __restrict__ bm,
    const float* __restrict__ h, const float* __restrict__ part,
    const float* __restrict__ Wu1, const float* __restrict__ bu1,
    const float* __restrict__ Wu2, const float* __restrict__ bu2,
    const float* __restrict__ Wmean, const float* __restrict__ bmean,
    const float* __restrict__ Wv, const float* __restrict__ bv,
    const float* __restrict__ log_std,
    float* __restrict__ out)
{
    __shared__ float hu[RI3][128];    // [h, msgs], later final u
    __shared__ float u1s[RI3][128];
    int t = threadIdx.x;
    int i0 = blockIdx.x * RI3;

    // stage h and finalize msgs from 4 partials
    for (int e = t; e < RI3 * 64; e += 1024) {
        int r = e >> 6, c = e & 63;
        int row = i0 + r;
        float s = part[(0 * N + row) * 64 + c] + part[(1 * N + row) * 64 + c]
                + part[(2 * N + row) * 64 + c] + part[(3 * N + row) * 64 + c];
        float q = p[row * 64 + c] - bm[c];
        hu[r][64 + c] = (s - (float)N * q) * (1.0f / N);
        hu[r][c] = h[row * 64 + c];
    }
    __syncthreads();

    int ch = t & 127, rg = t >> 7;    // rg 0..7 -> rows rg*3..rg*3+2
    {
        float u1[3] = {0.f, 0.f, 0.f};
        for (int k = 0; k < 128; ++k) {
            float w = Wu1[k * 128 + ch];
            #pragma unroll
            for (int i = 0; i < 3; ++i) u1[i] = fmaf(hu[rg * 3 + i][k], w, u1[i]);
        }
        float bias = bu1[ch];
        #pragma unroll
        for (int i = 0; i < 3; ++i) u1s[rg * 3 + i][ch] = fmaxf(0.f, u1[i] + bias);
    }
    __syncthreads();
    {
        float u2[3] = {0.f, 0.f, 0.f};
        for (int k = 0; k < 128; ++k) {
            float w = Wu2[k * 128 + ch];
            #pragma unroll
            for (int i = 0; i < 3; ++i) u2[i] = fmaf(u1s[rg * 3 + i][k], w, u2[i]);
        }
        float bias = bu2[ch];
        #pragma unroll
        for (int i = 0; i < 3; ++i) hu[rg * 3 + i][ch] = fmaxf(0.f, u2[i] + bias);
    }
    __syncthreads();

    // heads: wave g does rows g, g+16
    int g = t >> 6, lane = t & 63;
    for (int r = g; r < RI3; r += 16) {
        float a  = hu[r][lane];
        float b2 = hu[r][lane + 64];
        float m0 = a * Wmean[lane * 2 + 0] + b2 * Wmean[(lane + 64) * 2 + 0];
        float m1 = a * Wmean[lane * 2 + 1] + b2 * Wmean[(lane + 64) * 2 + 1];
        float vv = a * Wv[lane]            + b2 * Wv[lane + 64];
        #pragma unroll
        for (int off = 32; off > 0; off >>= 1) {
            m0 += __shfl_down(m0, off);
            m1 += __shfl_down(m1, off);
            vv += __shfl_down(vv, off);
        }
        if (lane == 0) {
            int row = i0 + r;
            out[row * 2 + 0] = m0 + bmean[0];
            out[row * 2 + 1] = m1 + bmean[1];
            out[3074 + row]  = vv + bv[0];
        }
    }
    if (blockIdx.x == 0 && t < 2) {
        out[3072 + t] = expf(log_std[t]);
    }
}

extern "C" void kernel_launch(void* const* d_in, const int* in_sizes, int n_in,
                              void* d_out, int out_size, void* d_ws, size_t ws_size,
                              hipStream_t stream) {
    const float* x      = (const float*)d_in[0];
    const float* W1     = (const float*)d_in[1];
    const float* b1     = (const float*)d_in[2];
    const float* W2     = (const float*)d_in[3];
    const float* b2     = (const float*)d_in[4];
    const float* Wm     = (const float*)d_in[5];
    const float* bm     = (const float*)d_in[6];
    const float* Wu1    = (const float*)d_in[7];
    const float* bu1    = (const float*)d_in[8];
    const float* Wu2    = (const float*)d_in[9];
    const float* bu2    = (const float*)d_in[10];
    const float* Wmean  = (const float*)d_in[11];
    const float* bmean  = (const float*)d_in[12];
    const float* Wv     = (const float*)d_in[13];
    const float* bv     = (const float*)d_in[14];
    const float* log_std= (const float*)d_in[15];
    float* out = (float*)d_out;

    float* ws   = (float*)d_ws;
    float* h    = ws;                  // N*64
    float* p    = ws + N * 64;         // N*64
    float* part = ws + 2 * N * 64;     // JS * N * 64

    enc_kernel<<<N / 6, 512, 0, stream>>>(x, W1, b1, W2, b2, Wm, h, p);
    msgA_kernel<<<(N / RI2) * JS, 1024, 0, stream>>>(p, bm, part);
    upd_kernel<<<N / RI3, 1024, 0, stream>>>(p, bm, h, part,
                                             Wu1, bu1, Wu2, bu2,
                                             Wmean, bmean, Wv, bv, log_std, out);
}

// Round 9
// 31.680 us; speedup vs baseline: 3.0551x; 3.0551x over previous
//
#include <hip/hip_runtime.h>

#define N 1536

// ---------------- K1: node encoder + message projection ----------------
// 256 blocks x 512 threads; 6 rows/block, float4 weight staging.
__global__ __launch_bounds__(512) void enc_kernel(
    const float* __restrict__ x, const float* __restrict__ W1, const float* __restrict__ b1,
    const float* __restrict__ W2, const float* __restrict__ b2,
    const float* __restrict__ Wm,
    float* __restrict__ h, float* __restrict__ p)
{
    __shared__ float sW2[64 * 64];
    __shared__ float sWm[64 * 64];
    __shared__ float buf1[6][64];
    __shared__ float buf2[6][64];
    int t = threadIdx.x;
    int w = t >> 6, c = t & 63;
    int i0 = blockIdx.x * 6;

    {
        const float4* W2v = (const float4*)W2;
        const float4* Wmv = (const float4*)Wm;
        float4* s2 = (float4*)sW2;
        float4* sm = (float4*)sWm;
        #pragma unroll
        for (int i = t; i < 1024; i += 512) { s2[i] = W2v[i]; sm[i] = Wmv[i]; }
    }

    if (w < 6) {
        int row = i0 + w;
        float4 xv = ((const float4*)x)[row];
        float h1 = xv.x * W1[0 * 64 + c] + xv.y * W1[1 * 64 + c]
                 + xv.z * W1[2 * 64 + c] + xv.w * W1[3 * 64 + c] + b1[c];
        buf1[w][c] = fmaxf(0.f, h1);
    }
    __syncthreads();

    if (w < 6) {
        int row = i0 + w;
        float h2 = b2[c];
        #pragma unroll
        for (int k = 0; k < 64; ++k) h2 = fmaf(buf1[w][k], sW2[k * 64 + c], h2);
        h2 = fmaxf(0.f, h2);
        h[row * 64 + c] = h2;
        buf2[w][c] = h2;

        float pv = 0.f;
        #pragma unroll
        for (int k = 0; k < 64; ++k) pv = fmaf(buf2[w][k], sWm[k * 64 + c], pv);
        p[row * 64 + c] = pv;
    }
}

// ---------------- K2: message-pass partials (2-D tiled, LDS slab) ----------------
// Grid 256 = 64 row-groups x 4 j-slices; 1024 threads = 16 waves =
// 4 rowgroups(6 rows each) x 4 j-subs(96 j each). Slab of 384 j staged in LDS.
// part[js][row][c] = sum_{j in slice} max(p[j,c], q[row,c]),  q = p[row,c]-bm[c]
#define RI2 24
#define JS  4
#define JPB (N / JS)     // 384 j per block
__global__ __launch_bounds__(1024) void msgA_kernel(
    const float* __restrict__ p, const float* __restrict__ bm,
    float* __restrict__ part)
{
    __shared__ float ps[JPB][64];      // 96 KB  (j-slab)
    __shared__ float qs[RI2][64];      // 6 KB
    __shared__ float red[16][6][64];   // 24 KB
    int t = threadIdx.x;
    int c = t & 63, g = t >> 6;        // wave 0..15
    int ig = blockIdx.x >> 2, js = blockIdx.x & 3;
    int i0 = ig * RI2;

    // stage q rows (24x64) and the 384x64 slab (float4, 6/thread)
    #pragma unroll
    for (int e = t; e < RI2 * 64; e += 1024) {
        int r = e >> 6, cc = e & 63;
        qs[r][cc] = p[(i0 + r) * 64 + cc] - bm[cc];
    }
    {
        const float4* pv = (const float4*)(p + js * JPB * 64);
        float4* psv = (float4*)ps;
        #pragma unroll
        for (int e = 0; e < 6; ++e) psv[t + e * 1024] = pv[t + e * 1024];
    }
    __syncthreads();

    int rg = g >> 2, jsub = g & 3;     // rowgroup, j-sub
    float q[6], acc[6];
    #pragma unroll
    for (int r = 0; r < 6; ++r) { q[r] = qs[rg * 6 + r][c]; acc[r] = 0.f; }

    const float* pslab = &ps[jsub * 96][0] + c;
    #pragma unroll
    for (int j = 0; j < 96; ++j) {
        float pj = pslab[j * 64];
        #pragma unroll
        for (int r = 0; r < 6; ++r) acc[r] += fmaxf(pj, q[r]);
    }

    #pragma unroll
    for (int r = 0; r < 6; ++r) red[g][r][c] = acc[r];
    __syncthreads();

    // combine 4 j-sub partials per row; 1536 entries, 1024 threads
    #pragma unroll
    for (int e = t; e < RI2 * 64; e += 1024) {
        int row = e >> 6, cc = e & 63;
        int rg2 = row / 6, rr = row - rg2 * 6;
        float s = red[rg2 * 4 + 0][rr][cc] + red[rg2 * 4 + 1][rr][cc]
                + red[rg2 * 4 + 2][rr][cc] + red[rg2 * 4 + 3][rr][cc];
        part[(js * N + i0 + row) * 64 + cc] = s;
    }
}

// ---------------- K3: reduce partials + update MLP + heads ----------------
// 64 blocks x 1024 threads, 24 rows per block.
#define RI3 24
__global__ __launch_bounds__(1024) void upd_kernel(
    const float* __restrict__ p, const float* __restrict__ bm,
    const float* __restrict__ h, const float* __restrict__ part,
    const float* __restrict__ Wu1, const float* __restrict__ bu1,
    const float* __restrict__ Wu2, const float* __restrict__ bu2,
    const float* __restrict__ Wmean, const float* __restrict__ bmean,
    const float* __restrict__ Wv, const float* __restrict__ bv,
    const float* __restrict__ log_std,
    float* __restrict__ out)
{
    __shared__ float hu[RI3][128];    // [h, msgs], later final u
    __shared__ float u1s[RI3][128];
    int t = threadIdx.x;
    int i0 = blockIdx.x * RI3;

    for (int e = t; e < RI3 * 64; e += 1024) {
        int r = e >> 6, c = e & 63;
        int row = i0 + r;
        float s = part[(0 * N + row) * 64 + c] + part[(1 * N + row) * 64 + c]
                + part[(2 * N + row) * 64 + c] + part[(3 * N + row) * 64 + c];
        float q = p[row * 64 + c] - bm[c];
        hu[r][64 + c] = (s - (float)N * q) * (1.0f / N);
        hu[r][c] = h[row * 64 + c];
    }
    __syncthreads();

    int ch = t & 127, rg = t >> 7;    // rg 0..7 -> rows rg*3..rg*3+2
    {
        float u1[3] = {0.f, 0.f, 0.f};
        for (int k = 0; k < 128; ++k) {
            float w = Wu1[k * 128 + ch];
            #pragma unroll
            for (int i = 0; i < 3; ++i) u1[i] = fmaf(hu[rg * 3 + i][k], w, u1[i]);
        }
        float bias = bu1[ch];
        #pragma unroll
        for (int i = 0; i < 3; ++i) u1s[rg * 3 + i][ch] = fmaxf(0.f, u1[i] + bias);
    }
    __syncthreads();
    {
        float u2[3] = {0.f, 0.f, 0.f};
        for (int k = 0; k < 128; ++k) {
            float w = Wu2[k * 128 + ch];
            #pragma unroll
            for (int i = 0; i < 3; ++i) u2[i] = fmaf(u1s[rg * 3 + i][k], w, u2[i]);
        }
        float bias = bu2[ch];
        #pragma unroll
        for (int i = 0; i < 3; ++i) hu[rg * 3 + i][ch] = fmaxf(0.f, u2[i] + bias);
    }
    __syncthreads();

    int g = t >> 6, lane = t & 63;
    for (int r = g; r < RI3; r += 16) {
        float a  = hu[r][lane];
        float b2 = hu[r][lane + 64];
        float m0 = a * Wmean[lane * 2 + 0] + b2 * Wmean[(lane + 64) * 2 + 0];
        float m1 = a * Wmean[lane * 2 + 1] + b2 * Wmean[(lane + 64) * 2 + 1];
        float vv = a * Wv[lane]            + b2 * Wv[lane + 64];
        #pragma unroll
        for (int off = 32; off > 0; off >>= 1) {
            m0 += __shfl_down(m0, off);
            m1 += __shfl_down(m1, off);
            vv += __shfl_down(vv, off);
        }
        if (lane == 0) {
            int row = i0 + r;
            out[row * 2 + 0] = m0 + bmean[0];
            out[row * 2 + 1] = m1 + bmean[1];
            out[3074 + row]  = vv + bv[0];
        }
    }
    if (blockIdx.x == 0 && t < 2) {
        out[3072 + t] = expf(log_std[t]);
    }
}

extern "C" void kernel_launch(void* const* d_in, const int* in_sizes, int n_in,
                              void* d_out, int out_size, void* d_ws, size_t ws_size,
                              hipStream_t stream) {
    const float* x      = (const float*)d_in[0];
    const float* W1     = (const float*)d_in[1];
    const float* b1     = (const float*)d_in[2];
    const float* W2     = (const float*)d_in[3];
    const float* b2     = (const float*)d_in[4];
    const float* Wm     = (const float*)d_in[5];
    const float* bm     = (const float*)d_in[6];
    const float* Wu1    = (const float*)d_in[7];
    const float* bu1    = (const float*)d_in[8];
    const float* Wu2    = (const float*)d_in[9];
    const float* bu2    = (const float*)d_in[10];
    const float* Wmean  = (const float*)d_in[11];
    const float* bmean  = (const float*)d_in[12];
    const float* Wv     = (const float*)d_in[13];
    const float* bv     = (const float*)d_in[14];
    const float* log_std= (const float*)d_in[15];
    float* out = (float*)d_out;

    float* ws   = (float*)d_ws;
    float* h    = ws;                  // N*64
    float* p    = ws + N * 64;         // N*64
    float* part = ws + 2 * N * 64;     // JS * N * 64

    enc_kernel<<<N / 6, 512, 0, stream>>>(x, W1, b1, W2, b2, Wm, h, p);
    msgA_kernel<<<(N / RI2) * JS, 1024, 0, stream>>>(p, bm, part);
    upd_kernel<<<N / RI3, 1024, 0, stream>>>(p, bm, h, part,
                                             Wu1, bu1, Wu2, bu2,
                                             Wmean, bmean, Wv, bv, log_std, out);
}